// Round 1
// baseline (240.215 us; speedup 1.0000x reference)
//
#include <hip/hip_runtime.h>
#include <hip/hip_bf16.h>

#define NN 2048
#define FIN 256
#define FOUT 256
#define HH 8

typedef short bhalf8 __attribute__((ext_vector_type(8)));   // 8 bf16 (4 VGPRs)
typedef float f32x4  __attribute__((ext_vector_type(4)));   // MFMA acc

__device__ __forceinline__ unsigned short f2b(float f) {
    __hip_bfloat16 h = __float2bfloat16(f);
    return *reinterpret_cast<unsigned short*>(&h);
}
__device__ __forceinline__ float b2f(unsigned short u) {
    __hip_bfloat16 h = *reinterpret_cast<__hip_bfloat16*>(&u);
    return __bfloat162float(h);
}

// ---------------------------------------------------------------- K1: qk & v
// 4 nodes per block; Wv L2-resident across blocks.
__global__ __launch_bounds__(256) void k1_qkv(
    const float* __restrict__ x, const float* __restrict__ Wq,
    const float* __restrict__ Wk, const float* __restrict__ Wv,
    float* __restrict__ v, float* __restrict__ qk)
{
    const int ib = blockIdx.x * 4;
    const int t  = threadIdx.x;
    __shared__ float xs[4][FIN];
    __shared__ float part[256];
    #pragma unroll
    for (int n = 0; n < 4; ++n) xs[n][t] = x[(long)(ib+n)*FIN + t];
    __syncthreads();
    float a0 = 0.f, a1 = 0.f, a2 = 0.f, a3 = 0.f;
    #pragma unroll 4
    for (int c = 0; c < FIN; ++c) {
        const float wv = Wv[c*FOUT + t];
        a0 = fmaf(xs[0][c], wv, a0); a1 = fmaf(xs[1][c], wv, a1);
        a2 = fmaf(xs[2][c], wv, a2); a3 = fmaf(xs[3][c], wv, a3);
    }
    v[(ib+0)*FOUT + t] = a0 * 0.0625f;
    v[(ib+1)*FOUT + t] = a1 * 0.0625f;
    v[(ib+2)*FOUT + t] = a2 * 0.0625f;
    v[(ib+3)*FOUT + t] = a3 * 0.0625f;
    {
        const int n = t >> 6, h = t & 7, seg = (t >> 3) & 7;
        float a = 0.f;
        for (int c = seg*32; c < seg*32 + 32; ++c)
            a = fmaf(xs[n][c], Wq[c*HH + h] + Wk[c*HH + h], a);
        part[t] = a;
    }
    __syncthreads();
    if (t < 32) {
        const int n = t >> 3, h = t & 7;
        float a = 0.f;
        #pragma unroll
        for (int s2 = 0; s2 < 8; ++s2) a += part[n*64 + s2*8 + h];
        qk[(ib+n)*HH + h] = a * (0.0625f * 0.35355339059327373f); // *scale/sqrt(8)
    }
}

// ------------------------------- K1b: vT_bf16[f][k] = bf16(v[k][f])  (1 MB)
__global__ __launch_bounds__(256) void k1b_vT(
    const float* __restrict__ v, unsigned short* __restrict__ vtb)
{
    const int k0 = blockIdx.x * 64;
    const int f0 = blockIdx.y * 64;
    const int t  = threadIdx.x;
    __shared__ float LT[64][68];
    const int r  = t >> 4;
    const int c4 = (t & 15) * 4;
    #pragma unroll
    for (int p = 0; p < 4; ++p) {
        const float4 q = *(const float4*)&v[(k0 + r + p*16)*FOUT + f0 + c4];
        LT[c4+0][r + p*16] = q.x; LT[c4+1][r + p*16] = q.y;
        LT[c4+2][r + p*16] = q.z; LT[c4+3][r + p*16] = q.w;
    }
    __syncthreads();
    #pragma unroll
    for (int p = 0; p < 4; ++p) {
        const int fr = r + p*16;
        ushort4 ub;
        ub.x = f2b(LT[fr][c4+0]); ub.y = f2b(LT[fr][c4+1]);
        ub.z = f2b(LT[fr][c4+2]); ub.w = f2b(LT[fr][c4+3]);
        *(ushort4*)&vtb[(long)(f0 + fr)*NN + k0 + c4] = ub;
    }
}

// ------------------------------------------------- K2: denoms + f-field + dd
// f[i,j] = masked ? -inf : cb*bond+cg*dist (bf16);  ddb[i,j] = bf16(-dist*deg)
// D[j,h] = sum_i exp(leaky(qk[i,h] + f[i,j]))
__global__ __launch_bounds__(256) void k2_denom(
    const float* __restrict__ bond, const float* __restrict__ dist,
    const float* __restrict__ deg, const float* __restrict__ qk,
    const float* __restrict__ wb, const float* __restrict__ wbc,
    const float* __restrict__ wg, float* __restrict__ D,
    unsigned short* __restrict__ fbuf, unsigned short* __restrict__ ddb)
{
    const float cb = wb[0] * wbc[0];
    const float cg = wg[0];
    const int tx = threadIdx.x & 63, ty = threadIdx.x >> 6;
    const int j  = blockIdx.x * 64 + tx;
    const int i0 = blockIdx.y * 64;
    __shared__ float qs[64*8];
    for (int p = threadIdx.x; p < 64*8; p += 256) qs[p] = qk[i0*8 + p];
    __syncthreads();
    float acc[8];
    #pragma unroll
    for (int h = 0; h < 8; ++h) acc[h] = 0.f;
    for (int ii = ty; ii < 64; ii += 4) {
        const long idx = (long)(i0 + ii)*NN + j;
        const float dv = dist[idx];
        const float gv = deg[idx];
        const float s0 = fmaf(cb, bond[idx], cg * dv);
        const unsigned short fb = f2b((gv > 0.f) ? s0 : -__builtin_inff());
        fbuf[idx] = fb;
        ddb[idx]  = f2b(-dv * gv);
        const float s = b2f(fb);            // rounded: consistent w/ k3
        #pragma unroll
        for (int h = 0; h < 8; ++h) {
            float r = qs[ii*8 + h] + s;
            r = (r > 0.f) ? r : 0.2f*r;
            acc[h] += __expf(r);            // masked: exp(-inf) = 0
        }
    }
    __shared__ float red[4][64][8];
    #pragma unroll
    for (int h = 0; h < 8; ++h) red[ty][tx][h] = acc[h];
    __syncthreads();
    for (int p = threadIdx.x; p < 512; p += 256) {
        const int jj = p >> 3, h = p & 7;
        const float ssum = red[0][jj][h] + red[1][jj][h] + red[2][jj][h] + red[3][jj][h];
        atomicAdd(&D[(blockIdx.x*64 + jj)*8 + h], ssum);
    }
}

// --------------------------- K3: attn_mean -> bf16 (reads only f-field + qk/D)
__global__ __launch_bounds__(256) void k3_attnmean(
    const unsigned short* __restrict__ fbuf, const float* __restrict__ qk,
    const float* __restrict__ D, unsigned short* __restrict__ amb)
{
    const int tx = threadIdx.x & 63, ty = threadIdx.x >> 6;
    const int j  = blockIdx.x * 64 + tx;
    const int i0 = blockIdx.y * 64;
    __shared__ float qs[64*8];
    for (int p = threadIdx.x; p < 64*8; p += 256) qs[p] = qk[i0*8 + p];
    __syncthreads();
    float invD[8];
    #pragma unroll
    for (int h = 0; h < 8; ++h) invD[h] = 0.125f / fmaxf(D[j*8 + h], 1e-30f);
    for (int ii = ty; ii < 64; ii += 4) {
        const long idx = (long)(i0 + ii)*NN + j;
        const float s = b2f(fbuf[idx]);
        float o = 0.f;
        #pragma unroll
        for (int h = 0; h < 8; ++h) {
            float r = qs[ii*8 + h] + s;
            r = (r > 0.f) ? r : 0.2f*r;
            o = fmaf(__expf(r), invD[h], o);   // masked: exp(-inf)=0 -> o=0
        }
        amb[idx] = f2b(o);
    }
}

// --------------- K4: partial[z] = am_bf(:, z) @ vT_bf(z, :)^T via MFMA
__global__ __launch_bounds__(256) void k4_aggr(
    const unsigned short* __restrict__ amb,
    const unsigned short* __restrict__ vtb, float* __restrict__ partial)
{
    const int i0 = blockIdx.x * 64;
    const int f0 = blockIdx.y * 64;
    const int k0 = blockIdx.z * 512;
    const int w  = threadIdx.x >> 6;
    const int l  = threadIdx.x & 63;
    const int lm = l & 15, lq = l >> 4;
    const int iw = i0 + w*16;
    f32x4 acc[4] = {f32x4{0,0,0,0}, f32x4{0,0,0,0}, f32x4{0,0,0,0}, f32x4{0,0,0,0}};
    for (int kk = k0; kk < k0 + 512; kk += 32) {
        const bhalf8 a = *(const bhalf8*)&amb[(long)(iw + lm)*NN + kk + lq*8];
        #pragma unroll
        for (int c = 0; c < 4; ++c) {
            const bhalf8 b = *(const bhalf8*)&vtb[(long)(f0 + c*16 + lm)*NN + kk + lq*8];
            acc[c] = __builtin_amdgcn_mfma_f32_16x16x32_bf16(a, b, acc[c], 0, 0, 0);
        }
    }
    float* out = partial + (long)blockIdx.z * NN * FOUT;
    #pragma unroll
    for (int c = 0; c < 4; ++c)
        #pragma unroll
        for (int r = 0; r < 4; ++r)
            out[(iw + lq*4 + r)*FOUT + f0 + c*16 + lm] = acc[c][r];
}

// ---------------- K4b: sum 4 partials + elu -> out0 (fp32) + un_bf16
__global__ __launch_bounds__(256) void k4b_elu(
    const float* __restrict__ partial, float* __restrict__ un,
    unsigned short* __restrict__ unb)
{
    const int idx = blockIdx.x*256 + threadIdx.x;
    const float4* p = (const float4*)partial;
    float4 s = p[idx];
    #pragma unroll
    for (int z = 1; z < 4; ++z) {
        const float4 q = p[idx + z*(NN*FOUT/4)];
        s.x += q.x; s.y += q.y; s.z += q.z; s.w += q.w;
    }
    s.x = (s.x > 0.f) ? s.x : (__expf(s.x) - 1.f);
    s.y = (s.y > 0.f) ? s.y : (__expf(s.y) - 1.f);
    s.z = (s.z > 0.f) ? s.z : (__expf(s.z) - 1.f);
    s.w = (s.w > 0.f) ? s.w : (__expf(s.w) - 1.f);
    ((float4*)un)[idx] = s;
    ushort4 ub; ub.x = f2b(s.x); ub.y = f2b(s.y); ub.z = f2b(s.z); ub.w = f2b(s.w);
    *(ushort4*)&unb[(long)idx*4] = ub;
}

// -------- K5: sim = un@un^T via MFMA; c0 = bf16(sigmoid(sim)*ddb); row stats
__global__ __launch_bounds__(256) void k5_sim(
    const unsigned short* __restrict__ unb, const unsigned short* __restrict__ ddb,
    unsigned short* __restrict__ c0,
    float* __restrict__ rowsum, float* __restrict__ rowsq)
{
    const int i0 = blockIdx.y * 64;
    const int j0 = blockIdx.x * 64;
    const int w  = threadIdx.x >> 6;
    const int l  = threadIdx.x & 63;
    const int lm = l & 15, lq = l >> 4;
    const int iw = i0 + w*16;
    f32x4 acc[4] = {f32x4{0,0,0,0}, f32x4{0,0,0,0}, f32x4{0,0,0,0}, f32x4{0,0,0,0}};
    for (int kk = 0; kk < FOUT; kk += 32) {
        const bhalf8 a = *(const bhalf8*)&unb[(long)(iw + lm)*FOUT + kk + lq*8];
        #pragma unroll
        for (int c = 0; c < 4; ++c) {
            const bhalf8 b = *(const bhalf8*)&unb[(long)(j0 + c*16 + lm)*FOUT + kk + lq*8];
            acc[c] = __builtin_amdgcn_mfma_f32_16x16x32_bf16(a, b, acc[c], 0, 0, 0);
        }
    }
    float srow[4] = {0.f,0.f,0.f,0.f}, qrow[4] = {0.f,0.f,0.f,0.f};
    #pragma unroll
    for (int c = 0; c < 4; ++c) {
        #pragma unroll
        for (int r = 0; r < 4; ++r) {
            const int i = iw + lq*4 + r;                 // C/D: row=(l>>4)*4+reg
            const int j = j0 + c*16 + lm;                //      col=l&15
            const long idx = (long)i*NN + j;
            const float sg = 1.f / (1.f + __expf(-acc[c][r]));
            const float val = sg * b2f(ddb[idx]);        // ddb = -dist*deg
            c0[idx] = f2b(val);
            srow[r] += val;
            qrow[r] = fmaf(val, val, qrow[r]);
        }
    }
    #pragma unroll
    for (int r = 0; r < 4; ++r) {
        #pragma unroll
        for (int m = 8; m >= 1; m >>= 1) {
            srow[r] += __shfl_xor(srow[r], m, 64);
            qrow[r] += __shfl_xor(qrow[r], m, 64);
        }
        if (lm == 0) {
            atomicAdd(&rowsum[iw + lq*4 + r], srow[r]);
            atomicAdd(&rowsq[iw + lq*4 + r],  qrow[r]);
        }
    }
}

// ------------------------------------------------------------- K6: mu / rstd
__global__ void k6_stats(const float* __restrict__ rowsum,
                         const float* __restrict__ rowsq,
                         float* __restrict__ mu, float* __restrict__ rs)
{
    const int i = blockIdx.x*256 + threadIdx.x;
    if (i < NN) {
        const float m = rowsum[i] * (1.f/NN);
        const float var = rowsq[i] * (1.f/NN) - m*m;
        mu[i] = m;
        rs[i] = rsqrtf(var + 1e-5f);
    }
}

// ------------------- K7: conn = norm(c0) + norm(c0)^T (c0 bf16 -> fp32 out)
__global__ __launch_bounds__(256) void k7_conn(
    const unsigned short* __restrict__ c0, const float* __restrict__ mu,
    const float* __restrict__ rs, float* __restrict__ out1)
{
    const int i0 = blockIdx.y * 64;
    const int j0 = blockIdx.x * 64;
    const int t  = threadIdx.x;
    __shared__ float LT[64][68];     // LT[i_local][j_local] = c0[j0+jl][i0+il]
    __shared__ float muj[64], rsj[64];
    const int r  = t >> 4;
    const int c4 = (t & 15) * 4;
    if (t < 64)        muj[t] = mu[j0 + t];
    else if (t < 128)  rsj[t-64] = rs[j0 + t - 64];
    #pragma unroll
    for (int p = 0; p < 4; ++p) {
        const int jl = r + p*16;
        const ushort4 q = *(const ushort4*)&c0[(long)(j0 + jl)*NN + i0 + c4];
        LT[c4+0][jl] = b2f(q.x); LT[c4+1][jl] = b2f(q.y);
        LT[c4+2][jl] = b2f(q.z); LT[c4+3][jl] = b2f(q.w);
    }
    __syncthreads();
    #pragma unroll
    for (int p = 0; p < 4; ++p) {
        const int rr = r + p*16;
        const int i  = i0 + rr;
        const ushort4 xb = *(const ushort4*)&c0[(long)i*NN + j0 + c4];
        const float mi = mu[i], ri = rs[i];
        float4 o;
        o.x = (b2f(xb.x) - mi)*ri + (LT[rr][c4+0] - muj[c4+0])*rsj[c4+0];
        o.y = (b2f(xb.y) - mi)*ri + (LT[rr][c4+1] - muj[c4+1])*rsj[c4+1];
        o.z = (b2f(xb.z) - mi)*ri + (LT[rr][c4+2] - muj[c4+2])*rsj[c4+2];
        o.w = (b2f(xb.w) - mi)*ri + (LT[rr][c4+3] - muj[c4+3])*rsj[c4+3];
        *(float4*)&out1[(long)i*NN + j0 + c4] = o;
    }
}

extern "C" void kernel_launch(void* const* d_in, const int* in_sizes, int n_in,
                              void* d_out, int out_size, void* d_ws, size_t ws_size,
                              hipStream_t stream)
{
    // Inputs fp32, outputs fp32 (established rounds 1-5).
    const float* x    = (const float*)d_in[0];
    const float* dist = (const float*)d_in[1];
    const float* bond = (const float*)d_in[2];
    // d_in[3] edge_direction: unused (only l=0 component couples; Y_0 = 1)
    const float* deg  = (const float*)d_in[4];
    const float* Wq   = (const float*)d_in[5];
    const float* Wk   = (const float*)d_in[6];
    const float* Wv   = (const float*)d_in[7];
    const float* wb   = (const float*)d_in[8];
    const float* wbc  = (const float*)d_in[9];
    const float* wg   = (const float*)d_in[10];

    float* out0 = (float*)d_out;            // updated_nodes: 2048*256 fp32
    float* out1 = out0 + (size_t)NN*FOUT;   // conn: 2048*2048 fp32

    // Workspace (~37.9 MB). Lifetime reuse: c0 (bf16, 8.4MB) overlays fbuf
    // (dead after k3). amb dead after k4; ddb dead after k5.
    char* w = (char*)d_ws;
    unsigned short* fbuf = (unsigned short*)(w);              //  8,388,608 B
    unsigned short* c0   = (unsigned short*)(w);              //  8,388,608 B (after k3)
    unsigned short* amb  = (unsigned short*)(w +  8388608);   //  8,388,608 B
    unsigned short* ddb  = (unsigned short*)(w + 16777216);   //  8,388,608 B
    float* partial = (float*)(w + 25165824);                  //  8,388,608 B (4 z)
    float* v       = (float*)(w + 33554432);                  //  2,097,152 B
    unsigned short* vtb = (unsigned short*)(w + 35651584);    //  1,048,576 B
    unsigned short* unb = (unsigned short*)(w + 36700160);    //  1,048,576 B
    float* qk      = (float*)(w + 37748736);                  //     65,536 B
    float* D       = (float*)(w + 37814272);                  //     65,536 B
    float* rowsum  = (float*)(w + 37879808);                  //      8,192 B
    float* rowsq   = (float*)(w + 37888000);                  //      8,192 B
    float* mu      = (float*)(w + 37896192);                  //      8,192 B
    float* rs      = (float*)(w + 37904384);                  //      8,192 B

    hipMemsetAsync(D, 0, 65536 + 8192 + 8192, stream);

    k1_qkv<<<NN/4, 256, 0, stream>>>(x, Wq, Wk, Wv, v, qk);
    dim3 g1b(NN/64, FOUT/64);
    k1b_vT<<<g1b, 256, 0, stream>>>(v, vtb);
    dim3 g23(NN/64, NN/64);
    k2_denom<<<g23, 256, 0, stream>>>(bond, dist, deg, qk, wb, wbc, wg, D, fbuf, ddb);
    k3_attnmean<<<g23, 256, 0, stream>>>(fbuf, qk, D, amb);
    dim3 g4(NN/64, FOUT/64, 4);
    k4_aggr<<<g4, 256, 0, stream>>>(amb, vtb, partial);
    k4b_elu<<<NN*FOUT/4/256, 256, 0, stream>>>(partial, out0, unb);
    dim3 g5(NN/64, NN/64);
    k5_sim<<<g5, 256, 0, stream>>>(unb, ddb, c0, rowsum, rowsq);
    k6_stats<<<8, 256, 0, stream>>>(rowsum, rowsq, mu, rs);
    k7_conn<<<g5, 256, 0, stream>>>(c0, mu, rs, out1);
}